// Round 8
// baseline (1851.892 us; speedup 1.0000x reference)
//
#include <hip/hip_runtime.h>

typedef short bf16x8 __attribute__((ext_vector_type(8)));
typedef float f32x16 __attribute__((ext_vector_type(16)));

#define BIG_F 1e10f
constexpr int B = 16;
constexpr int N = 4096;
constexpr int COLS = 512;          // y-cols per block
constexpr int NCB = N / COLS;      // 8 col-blocks
constexpr int JOBS = 4;            // row-jobs per block (128 rows each)
constexpr int SUBROWS = 128 * JOBS;// 512 rows per block
constexpr int NSB = N / SUBROWS;   // 8 row-superblocks

// truncating bf16 hi/lo split: v ~= hi + lo
__device__ __forceinline__ void split(float v, unsigned& h, unsigned& l) {
    unsigned hb = __float_as_uint(v) & 0xFFFF0000u;
    h = hb >> 16;
    float r = v - __uint_as_float(hb);
    l = __float_as_uint(r) >> 16;
}

__device__ __forceinline__ float min3f(float a, float b, float c) {
    return fminf(fminf(a, b), c);   // fuses to v_min3_f32
}

__device__ __forceinline__ float vmin16(f32x16 C) {
    float u0 = min3f(C[0], C[1], C[2]);
    float u1 = min3f(C[3], C[4], C[5]);
    float u2 = min3f(C[6], C[7], C[8]);
    float u3 = min3f(C[9], C[10], C[11]);
    float u4 = min3f(C[12], C[13], C[14]);
    return min3f(min3f(u0, u1, u2), fminf(u3, u4), C[15]);
}

// VALU-pipe cross-lane min via DPP (no ds-op). ctrl must be a literal.
#define DPP_MIN(v, ctrl)                                                      \
    v = fminf(v, __int_as_float(__builtin_amdgcn_update_dpp(                  \
            __float_as_int(v), __float_as_int(v), (ctrl), 0xF, 0xF, false)))

// P[n,m] = xx[n] + yy[m] - 2 x_n . y_m (+BIG masked) via mfma_f32_32x32x16_bf16:
//   A_k(n) = [ah0..2, ah0..2, al0..2, al0..2, xxh, xxl, 1, 1]  (ah+al = -2x)
//   B_k(m) = [yh0..2, yl0..2, yh0..2, yl0..2, 1, 1, qh, ql]    (qh+ql = yy)
// Block = (b, cb, sub): stages+packs B-slice (b,cb) ONCE, runs 4 row-jobs
// (rb = sub*4+jj). Row-min lane-reduce on the VALU pipe via DPP
// (quad xor1, xor2, row_ror4, row_ror8 -> per-16-lane-row min); the xor16
// step is skipped by emitting TWO col-subset rowpart slabs. Col-mins live in
// cm[16] regs across jobs; one colbuf pass per block. 2 barriers total.
// NO grid.sync anywhere (R6: 2x grid.sync = 8-XCD L2 flush, 207us).
__global__ __launch_bounds__(256, 4) void chamfer_mfma(
    const float* __restrict__ x, const float* __restrict__ y,
    const int* __restrict__ mask,
    float* __restrict__ rowpart,   // [B][NCB][2][N] row-min partials
    float* __restrict__ colpart,   // [B][NSB][N]    col-min partials (512 rows)
    float* __restrict__ out)
{
    const int blk = blockIdx.x;     // 0..1023
    const int b   = blk >> 6;
    const int cb  = (blk >> 3) & 7;
    const int sub = blk & 7;
    const int t   = threadIdx.x;

    __shared__ __align__(16) unsigned short Bpack[2][COLS][8];  // 16 KB
    __shared__ float colbuf[8][COLS];                           // 16 KB

    if (blk == 0 && t == 0) out[0] = 0.0f;   // finalize is the next dispatch

    const float* xb = x + (size_t)b * 3 * N;
    const float* yb = y + (size_t)b * 3 * N;
    const int*   mb = mask + b * N;

    // ---- pack this block's 512-col B slice (2 points/thread) ----
#pragma unroll
    for (int i = 0; i < 2; ++i) {
        int c = t + i * 256;
        int m = cb * COLS + c;
        float y0 = yb[m], y1 = yb[N + m], y2 = yb[2 * N + m];
        float madd = mb[m] ? 0.0f : BIG_F;
        float yy = fmaf(y2, y2, fmaf(y1, y1, y0 * y0)) + madd;
        unsigned h0, l0, h1, l1, h2, l2, qh, ql;
        split(y0, h0, l0);
        split(y1, h1, l1);
        split(y2, h2, l2);
        split(yy, qh, ql);
        unsigned u0 = h0 | (h1 << 16);
        unsigned u1 = h2 | (l0 << 16);
        unsigned u2 = l1 | (l2 << 16);
        uint4 w0 = { u0, u1, u2, u0 };
        uint4 w1 = { u1, u2, 0x3F803F80u, qh | (ql << 16) };
        *(uint4*)&Bpack[0][c][0] = w0;
        *(uint4*)&Bpack[1][c][0] = w1;
    }

    const int w    = t >> 6;    // wave 0..3, rows w*32..w*32+31 within a job
    const int L    = t & 63;
    const int half = L >> 5;    // k-half 0/1
    const int lc   = L & 31;

    // first job's x-point loads (issued before the barrier to hide latency)
    int n0 = sub * SUBROWS + w * 32 + lc;
    float nx0 = xb[n0], nx1 = xb[N + n0], nx2 = xb[2 * N + n0];
    float nmadd = mb[n0] ? 0.0f : BIG_F;

    __syncthreads();

    const unsigned short* Bb = &Bpack[half][lc][0];  // +p*512 shorts = col p*64+lc

    float cm[16];
#pragma unroll
    for (int i = 0; i < 16; ++i) cm[i] = 1e30f;

    const f32x16 z16 = {0.f,0.f,0.f,0.f,0.f,0.f,0.f,0.f,
                        0.f,0.f,0.f,0.f,0.f,0.f,0.f,0.f};

#pragma unroll 1
    for (int jj = 0; jj < JOBS; ++jj) {
        // build A fragment from prefetched point
        float xx = fmaf(nx2, nx2, fmaf(nx1, nx1, nx0 * nx0)) + nmadd;
        unsigned h0, l0, h1, l1, h2, l2, xh, xl;
        split(-2.0f * nx0, h0, l0);
        split(-2.0f * nx1, h1, l1);
        split(-2.0f * nx2, h2, l2);
        split(xx, xh, xl);
        uint4 wa;
        wa.x = half ? (l2 | (l0 << 16)) : (h0 | (h1 << 16));
        wa.y = half ? (l1 | (l2 << 16)) : (h2 | (h0 << 16));
        wa.z = half ? (xh | (xl << 16)) : (h1 | (h2 << 16));
        wa.w = half ? 0x3F803F80u       : (l0 | (l1 << 16));
        bf16x8 afr = *(bf16x8*)&wa;

        // prefetch next job's point (issues before the MFMA loop)
        if (jj + 1 < JOBS) {
            int n = sub * SUBROWS + (jj + 1) * 128 + w * 32 + lc;
            nx0 = xb[n]; nx1 = xb[N + n]; nx2 = xb[2 * N + n];
            nmadd = mb[n] ? 0.0f : BIG_F;
        }

        float rm[16];
#pragma unroll
        for (int r = 0; r < 16; ++r) rm[r] = 1e30f;

#pragma unroll
        for (int p = 0; p < 8; ++p) {          // fully unrolled: cm/rm static
            if ((p & 1) == 0) asm volatile("" ::: "memory");  // no mass hoist
            bf16x8 bf0 = *(const bf16x8*)(Bb + p * 512);
            bf16x8 bf1 = *(const bf16x8*)(Bb + p * 512 + 256);
            f32x16 C0 = __builtin_amdgcn_mfma_f32_32x32x16_bf16(afr, bf0, z16, 0, 0, 0);
            f32x16 C1 = __builtin_amdgcn_mfma_f32_32x32x16_bf16(afr, bf1, z16, 0, 0, 0);
            // C[r]: row = w*32 + (r&3)+8*(r>>2)+4*half, col = p*64(+32)+lc
#pragma unroll
            for (int r = 0; r < 16; ++r) rm[r] = min3f(rm[r], C0[r], C1[r]);
            cm[2 * p]     = fminf(cm[2 * p],     vmin16(C0));
            cm[2 * p + 1] = fminf(cm[2 * p + 1], vmin16(C1));
        }

        // row-min over each 16-lane group, entirely on the VALU pipe.
        // (quad xor1, xor2 complete quads; ror4+ror8 then cover all 4 quads)
#pragma unroll
        for (int r = 0; r < 16; ++r) {
            DPP_MIN(rm[r], 0xB1);    // quad_perm {1,0,3,2}  = xor1
            DPP_MIN(rm[r], 0x4E);    // quad_perm {2,3,0,1}  = xor2
            DPP_MIN(rm[r], 0x124);   // row_ror:4
            DPP_MIN(rm[r], 0x128);   // row_ror:8
        }
        if ((lc & 15) == 0) {        // lanes 0,16,32,48: (half, col-subset)
            int sset = lc >> 4;      // cols with (c&63) in sset*16+[0,15] U 32+...
            float* rp = rowpart + (((size_t)(b * NCB + cb)) * 2 + sset) * N
                      + sub * SUBROWS + jj * 128 + w * 32 + half * 4;
            *(float4*)(rp +  0) = make_float4(rm[0],  rm[1],  rm[2],  rm[3]);
            *(float4*)(rp +  8) = make_float4(rm[4],  rm[5],  rm[6],  rm[7]);
            *(float4*)(rp + 16) = make_float4(rm[8],  rm[9],  rm[10], rm[11]);
            *(float4*)(rp + 24) = make_float4(rm[12], rm[13], rm[14], rm[15]);
        }
    }

    // ---- col partials: one LDS pass per block ----
    {
        float* cw = &colbuf[w * 2 + half][lc];
#pragma unroll
        for (int p = 0; p < 8; ++p) {
            cw[p * 64]      = cm[2 * p];
            cw[p * 64 + 32] = cm[2 * p + 1];
        }
    }
    __syncthreads();
    if (t < 128) {                   // combine 8 (wave,half) slabs, float4-wide
        const float4* cb4 = (const float4*)&colbuf[0][0];
        float4 v = cb4[t];
#pragma unroll
        for (int s = 1; s < 8; ++s) {
            float4 u = cb4[s * 128 + t];
            v.x = fminf(v.x, u.x); v.y = fminf(v.y, u.y);
            v.z = fminf(v.z, u.z); v.w = fminf(v.w, u.w);
        }
        *(float4*)(colpart + ((size_t)b * NSB + sub) * N + cb * COLS + t * 4) = v;
    }
}

__global__ __launch_bounds__(256) void finalize_kernel(
    const int* __restrict__ mask,
    const float* __restrict__ rowpart, const float* __restrict__ colpart,
    float* __restrict__ out)
{
    const int b = blockIdx.x & 15;
    const int q = blockIdx.x >> 4;   // quarter 0..3
    const int t = threadIdx.x;
    const int* mrow = mask + b * N;

    int cnt = 0;
    for (int i = t; i < N / 4; i += 256) {
        int4 mk = ((const int4*)mrow)[i];
        cnt += mk.x + mk.y + mk.z + mk.w;
    }

    const int p0 = q * 1024 + t * 4;

    // col-min over 8 superblock slabs
    const float* cp = colpart + (size_t)b * NSB * N + p0;
    float4 mn = *(const float4*)cp;
#pragma unroll
    for (int pb = 1; pb < NSB; ++pb) {
        float4 v = *(const float4*)(cp + (size_t)pb * N);
        mn.x = fminf(mn.x, v.x); mn.y = fminf(mn.y, v.y);
        mn.z = fminf(mn.z, v.z); mn.w = fminf(mn.w, v.w);
    }
    // row-min over 16 (cb, subset) slabs
    const float* rp = rowpart + (size_t)b * NCB * 2 * N + p0;
    float4 rn = *(const float4*)rp;
#pragma unroll 4
    for (int pb = 1; pb < NCB * 2; ++pb) {
        float4 v = *(const float4*)(rp + (size_t)pb * N);
        rn.x = fminf(rn.x, v.x); rn.y = fminf(rn.y, v.y);
        rn.z = fminf(rn.z, v.z); rn.w = fminf(rn.w, v.w);
    }
    int4 mk = *(const int4*)(mrow + p0);
    float s = (mk.x ? (mn.x + rn.x) : 0.f) + (mk.y ? (mn.y + rn.y) : 0.f)
            + (mk.z ? (mn.z + rn.z) : 0.f) + (mk.w ? (mn.w + rn.w) : 0.f);

    for (int off = 32; off > 0; off >>= 1) {
        s   += __shfl_down(s, off);
        cnt += __shfl_down(cnt, off);
    }
    __shared__ float rs[4];
    __shared__ int   rc[4];
    const int wv = t >> 6;
    if ((t & 63) == 0) { rs[wv] = s; rc[wv] = cnt; }
    __syncthreads();
    if (t == 0) {
        float S = rs[0] + rs[1] + rs[2] + rs[3];
        float C = (float)(rc[0] + rc[1] + rc[2] + rc[3]);
        atomicAdd(out, (S / C) * (1.0f / 16.0f));
    }
}

extern "C" void kernel_launch(void* const* d_in, const int* in_sizes, int n_in,
                              void* d_out, int out_size, void* d_ws, size_t ws_size,
                              hipStream_t stream) {
    const float* x    = (const float*)d_in[0];
    const float* y    = (const float*)d_in[1];
    const int*   mask = (const int*)d_in[2];

    float* rowpart = (float*)d_ws;                        // B*NCB*2*N = 4 MB
    float* colpart = rowpart + (size_t)B * NCB * 2 * N;   // B*NSB*N   = 2 MB

    chamfer_mfma<<<dim3(B * NCB * NSB), 256, 0, stream>>>(
        x, y, mask, rowpart, colpart, (float*)d_out);
    finalize_kernel<<<dim3(64), 256, 0, stream>>>(
        mask, rowpart, colpart, (float*)d_out);
}

// Round 9
// 91.886 us; speedup vs baseline: 20.1543x; 20.1543x over previous
//
#include <hip/hip_runtime.h>

typedef short bf16x8 __attribute__((ext_vector_type(8)));
typedef float f32x16 __attribute__((ext_vector_type(16)));

#define BIG_F 1e10f
constexpr int B = 16;
constexpr int N = 4096;
constexpr int ROWS = 128;         // x-rows per block
constexpr int COLS = 512;         // y-cols per block
constexpr int NRB = N / ROWS;     // 32 row-blocks
constexpr int NCB = N / COLS;     // 8 col-blocks

// truncating bf16 hi/lo split: v ~= hi + lo
__device__ __forceinline__ void split(float v, unsigned& h, unsigned& l) {
    unsigned hb = __float_as_uint(v) & 0xFFFF0000u;
    h = hb >> 16;
    float r = v - __uint_as_float(hb);
    l = __float_as_uint(r) >> 16;
}

__device__ __forceinline__ float min3f(float a, float b, float c) {
    return fminf(fminf(a, b), c);   // fuses to v_min3_f32
}

__device__ __forceinline__ float vmin16(f32x16 C) {
    float u0 = min3f(C[0], C[1], C[2]);
    float u1 = min3f(C[3], C[4], C[5]);
    float u2 = min3f(C[6], C[7], C[8]);
    float u3 = min3f(C[9], C[10], C[11]);
    float u4 = min3f(C[12], C[13], C[14]);
    return min3f(min3f(u0, u1, u2), fminf(u3, u4), C[15]);
}

// VALU-pipe cross-lane min via DPP (no ds-op). ctrl must be a literal.
// Validated exact in R8 (absmax 0).
#define DPP_MIN(v, ctrl)                                                      \
    v = fminf(v, __int_as_float(__builtin_amdgcn_update_dpp(                  \
            __float_as_int(v), __float_as_int(v), (ctrl), 0xF, 0xF, false)))

// P[n,m] = xx[n] + yy[m] - 2 x_n . y_m (+BIG masked) via mfma_f32_32x32x16_bf16:
//   A_k(n) = [ah0..2, ah0..2, al0..2, al0..2, xxh, xxl, 1, 1]  (ah+al = -2x)
//   B_k(m) = [yh0..2, yl0..2, yh0..2, yl0..2, 1, 1, qh, ql]    (qh+ql = yy)
// One 128x512 job per block (grid 4096). Lean body: rm[16] + ONE C-pair in
// flight, unroll 1 — the only register shape that holds at (256,4) without
// spill (R5 ok; R3/R8 heavier bodies -> 64-VGPR spill collapse, GBs of
// scratch). Col-mins go straight to colbuf[8][*] (no in-loop shfl); row-min
// epilogue is all-DPP on the VALU pipe with two col-subset rowpart slabs.
__global__ __launch_bounds__(256, 4) void chamfer_mfma(
    const float* __restrict__ x, const float* __restrict__ y,
    const int* __restrict__ mask,
    float* __restrict__ rowpart,   // [B][NCB][2][N] row-min partials (sset slabs)
    float* __restrict__ colpart,   // [B][NRB][N]    col-min partials (128 rows)
    float* __restrict__ out)
{
    const int rb = blockIdx.x & 31;   // consecutive blocks share the y-slice (L2)
    const int cb = blockIdx.x >> 5;
    const int b  = blockIdx.y;
    const int t  = threadIdx.x;

    __shared__ __align__(16) unsigned short Bpack[2][COLS][8];  // 16 KB
    __shared__ float colbuf[8][COLS];                           // 16 KB

    if (blockIdx.x == 0 && b == 0 && t == 0) out[0] = 0.0f;  // finalize is next

    const float* xb = x + (size_t)b * 3 * N;
    const float* yb = y + (size_t)b * 3 * N;
    const int*   mb = mask + b * N;

    // ---- pack this block's 512-col B slice (2 points/thread) ----
#pragma unroll
    for (int i = 0; i < 2; ++i) {
        int c = t + i * 256;
        int m = cb * COLS + c;
        float y0 = yb[m], y1 = yb[N + m], y2 = yb[2 * N + m];
        float madd = mb[m] ? 0.0f : BIG_F;
        float yy = fmaf(y2, y2, fmaf(y1, y1, y0 * y0)) + madd;
        unsigned h0, l0, h1, l1, h2, l2, qh, ql;
        split(y0, h0, l0);
        split(y1, h1, l1);
        split(y2, h2, l2);
        split(yy, qh, ql);
        unsigned u0 = h0 | (h1 << 16);
        unsigned u1 = h2 | (l0 << 16);
        unsigned u2 = l1 | (l2 << 16);
        uint4 w0 = { u0, u1, u2, u0 };
        uint4 w1 = { u1, u2, 0x3F803F80u, qh | (ql << 16) };
        *(uint4*)&Bpack[0][c][0] = w0;
        *(uint4*)&Bpack[1][c][0] = w1;
    }

    const int w    = t >> 6;    // wave 0..3, rows w*32..w*32+31
    const int L    = t & 63;
    const int half = L >> 5;    // k-half 0/1
    const int lc   = L & 31;

    // ---- A fragment built in-register for own row (no LDS, no barrier) ----
    bf16x8 afr;
    {
        int n = rb * ROWS + w * 32 + lc;
        float x0 = xb[n], x1 = xb[N + n], x2 = xb[2 * N + n];
        float madd = mb[n] ? 0.0f : BIG_F;
        float xx = fmaf(x2, x2, fmaf(x1, x1, x0 * x0)) + madd;
        unsigned h0, l0, h1, l1, h2, l2, xh, xl;
        split(-2.0f * x0, h0, l0);
        split(-2.0f * x1, h1, l1);
        split(-2.0f * x2, h2, l2);
        split(xx, xh, xl);
        uint4 wa;
        wa.x = half ? (l2 | (l0 << 16)) : (h0 | (h1 << 16));
        wa.y = half ? (l1 | (l2 << 16)) : (h2 | (h0 << 16));
        wa.z = half ? (xh | (xl << 16)) : (h1 | (h2 << 16));
        wa.w = half ? 0x3F803F80u       : (l0 | (l1 << 16));
        afr = *(bf16x8*)&wa;
    }

    __syncthreads();

    const unsigned short* Bb = &Bpack[half][lc][0];  // +p*512 shorts = col p*64+lc

    float rm[16];
#pragma unroll
    for (int r = 0; r < 16; ++r) rm[r] = 1e30f;

    const f32x16 z16 = {0.f,0.f,0.f,0.f,0.f,0.f,0.f,0.f,
                        0.f,0.f,0.f,0.f,0.f,0.f,0.f,0.f};

#pragma unroll 1
    for (int p = 0; p < 8; ++p) {          // 8 col-pairs of 32 = 512 cols
        bf16x8 bf0 = *(const bf16x8*)(Bb + p * 512);
        bf16x8 bf1 = *(const bf16x8*)(Bb + p * 512 + 256);
        f32x16 C0 = __builtin_amdgcn_mfma_f32_32x32x16_bf16(afr, bf0, z16, 0, 0, 0);
        f32x16 C1 = __builtin_amdgcn_mfma_f32_32x32x16_bf16(afr, bf1, z16, 0, 0, 0);
        // C[r]: row = w*32 + (r&3)+8*(r>>2)+4*half, col = p*64(+32)+lc
#pragma unroll
        for (int r = 0; r < 16; ++r) rm[r] = min3f(rm[r], C0[r], C1[r]);
        // col partials over this half's 16 rows -> LDS (no shfl on critical path)
        colbuf[w * 2 + half][p * 64 + lc]      = vmin16(C0);
        colbuf[w * 2 + half][p * 64 + 32 + lc] = vmin16(C1);
    }

    // ---- row-min over each 16-lane group, entirely on the VALU pipe ----
#pragma unroll
    for (int r = 0; r < 16; ++r) {
        DPP_MIN(rm[r], 0xB1);    // quad_perm {1,0,3,2}  = xor1
        DPP_MIN(rm[r], 0x4E);    // quad_perm {2,3,0,1}  = xor2
        DPP_MIN(rm[r], 0x124);   // row_ror:4
        DPP_MIN(rm[r], 0x128);   // row_ror:8
    }
    if ((lc & 15) == 0) {        // lanes 0,16,32,48: (half, col-subset)
        int sset = lc >> 4;      // min over cols with (c&63) in sset*16+[0,15]+{0,32}
        float* rp = rowpart + (((size_t)(b * NCB + cb)) * 2 + sset) * N
                  + rb * ROWS + w * 32 + half * 4;
        *(float4*)(rp +  0) = make_float4(rm[0],  rm[1],  rm[2],  rm[3]);
        *(float4*)(rp +  8) = make_float4(rm[4],  rm[5],  rm[6],  rm[7]);
        *(float4*)(rp + 16) = make_float4(rm[8],  rm[9],  rm[10], rm[11]);
        *(float4*)(rp + 24) = make_float4(rm[12], rm[13], rm[14], rm[15]);
    }

    __syncthreads();
    if (t < 128) {                   // combine 8 (wave,half) slabs, float4-wide
        const float4* cb4 = (const float4*)&colbuf[0][0];
        float4 v = cb4[t];
#pragma unroll
        for (int s = 1; s < 8; ++s) {
            float4 u = cb4[s * 128 + t];
            v.x = fminf(v.x, u.x); v.y = fminf(v.y, u.y);
            v.z = fminf(v.z, u.z); v.w = fminf(v.w, u.w);
        }
        *(float4*)(colpart + ((size_t)b * NRB + rb) * N + cb * COLS + t * 4) = v;
    }
}

__global__ __launch_bounds__(256) void finalize_kernel(
    const int* __restrict__ mask,
    const float* __restrict__ rowpart, const float* __restrict__ colpart,
    float* __restrict__ out)
{
    const int b = blockIdx.x & 15;
    const int q = blockIdx.x >> 4;   // quarter 0..3
    const int t = threadIdx.x;
    const int* mrow = mask + b * N;

    int cnt = 0;
    for (int i = t; i < N / 4; i += 256) {
        int4 mk = ((const int4*)mrow)[i];
        cnt += mk.x + mk.y + mk.z + mk.w;
    }

    const int p0 = q * 1024 + t * 4;

    // col-min over 32 row-block slabs
    const float* cp = colpart + (size_t)b * NRB * N + p0;
    float4 mn = *(const float4*)cp;
#pragma unroll 4
    for (int pb = 1; pb < NRB; ++pb) {
        float4 v = *(const float4*)(cp + (size_t)pb * N);
        mn.x = fminf(mn.x, v.x); mn.y = fminf(mn.y, v.y);
        mn.z = fminf(mn.z, v.z); mn.w = fminf(mn.w, v.w);
    }
    // row-min over 16 (cb, subset) slabs
    const float* rp = rowpart + (size_t)b * NCB * 2 * N + p0;
    float4 rn = *(const float4*)rp;
#pragma unroll 4
    for (int pb = 1; pb < NCB * 2; ++pb) {
        float4 v = *(const float4*)(rp + (size_t)pb * N);
        rn.x = fminf(rn.x, v.x); rn.y = fminf(rn.y, v.y);
        rn.z = fminf(rn.z, v.z); rn.w = fminf(rn.w, v.w);
    }
    int4 mk = *(const int4*)(mrow + p0);
    float s = (mk.x ? (mn.x + rn.x) : 0.f) + (mk.y ? (mn.y + rn.y) : 0.f)
            + (mk.z ? (mn.z + rn.z) : 0.f) + (mk.w ? (mn.w + rn.w) : 0.f);

    for (int off = 32; off > 0; off >>= 1) {
        s   += __shfl_down(s, off);
        cnt += __shfl_down(cnt, off);
    }
    __shared__ float rs[4];
    __shared__ int   rc[4];
    const int wv = t >> 6;
    if ((t & 63) == 0) { rs[wv] = s; rc[wv] = cnt; }
    __syncthreads();
    if (t == 0) {
        float S = rs[0] + rs[1] + rs[2] + rs[3];
        float C = (float)(rc[0] + rc[1] + rc[2] + rc[3]);
        atomicAdd(out, (S / C) * (1.0f / 16.0f));
    }
}

extern "C" void kernel_launch(void* const* d_in, const int* in_sizes, int n_in,
                              void* d_out, int out_size, void* d_ws, size_t ws_size,
                              hipStream_t stream) {
    const float* x    = (const float*)d_in[0];
    const float* y    = (const float*)d_in[1];
    const int*   mask = (const int*)d_in[2];

    float* rowpart = (float*)d_ws;                        // B*NCB*2*N = 4 MB
    float* colpart = rowpart + (size_t)B * NCB * 2 * N;   // B*NRB*N   = 8 MB

    chamfer_mfma<<<dim3(NRB * NCB, B), 256, 0, stream>>>(
        x, y, mask, rowpart, colpart, (float*)d_out);
    finalize_kernel<<<dim3(64), 256, 0, stream>>>(
        mask, rowpart, colpart, (float*)d_out);
}